// Round 4
// baseline (819.063 us; speedup 1.0000x reference)
//
#include <hip/hip_runtime.h>

#define NN 100000
#define NE 1600000
#define HID 64
#define NBUK 391              // buckets of 256 node ids: (NN+255)/256
#define CAP 6144              // per-bucket capacity; mean 4096, sd 64 -> +32 sigma
#define SRCBITS 17
#define SRCMASK 0x1FFFF

// ---- init: detect edge dtype (int64 vs int32) + zero bucket cursors --------
__global__ void k_init(const int* __restrict__ ei, int* __restrict__ flag,
                       int* __restrict__ bcur) {
    int t = threadIdx.x;  // 256
    if (t < 64) {
        int v = ei[2 * t + 1];
        unsigned long long b = __ballot(v != 0);
        if (t == 0) *flag = (b == 0ULL) ? 1 : 0;  // 1 => int64 layout
    }
    for (int i = t; i < NBUK; i += 256) bcur[i] = 0;
}

__device__ __forceinline__ int ld_idx(const int* __restrict__ ei, int off, int is64) {
    return is64 ? ei[2 * off] : ei[off];
}

// ---- pass A: bucket edges by dst>>8, packed (dstLow<<17)|src ---------------
__global__ void k_passA(const int* __restrict__ ei, const int* __restrict__ flag,
                        int* __restrict__ bcur, unsigned int* __restrict__ bbuf) {
    int t = threadIdx.x;
    int base = blockIdx.x * 4096;
    int f = *flag;
#pragma unroll
    for (int k = 0; k < 16; ++k) {
        int e = base + k * 256 + t;
        if (e >= NE) break;
        int s = ld_idx(ei, e, f);
        int d = ld_idx(ei, NE + e, f);
        int b = d >> 8;
        int p = atomicAdd(&bcur[b], 1);
        bbuf[b * CAP + p] = ((unsigned int)(d & 255) << SRCBITS) | (unsigned int)s;
    }
}

// ---- scan 391 bucket sizes -> csr base per bucket --------------------------
__global__ void k_scanb(const int* __restrict__ bcur, int* __restrict__ bbase) {
    __shared__ int s[512];
    int t = threadIdx.x;  // 512
    int v = (t < NBUK) ? bcur[t] : 0;
    s[t] = v; __syncthreads();
    for (int off = 1; off < 512; off <<= 1) {
        int u = (t >= off) ? s[t - off] : 0;
        __syncthreads();
        s[t] += u;
        __syncthreads();
    }
    if (t < NBUK) bbase[t] = s[t] - v;  // exclusive
}

// ---- pass B: per-bucket histogram -> cnt/dinv/xs/offs, then csr fill -------
__global__ void k_passB(const unsigned int* __restrict__ bbuf, const int* __restrict__ bcur,
                        const int* __restrict__ bbase, const float* __restrict__ x,
                        int* __restrict__ cnt, int* __restrict__ offs,
                        float* __restrict__ dinv, float* __restrict__ xs,
                        int* __restrict__ csr) {
    __shared__ int hist[256];
    __shared__ int scn[256];
    __shared__ int cur[256];
    int t = threadIdx.x;  // 256
    int b = blockIdx.x;
    int sz = bcur[b];
    const unsigned int* buf = bbuf + b * CAP;
    hist[t] = 0;
    __syncthreads();
    for (int e = t; e < sz; e += 256)
        atomicAdd(&hist[buf[e] >> SRCBITS], 1);
    __syncthreads();
    int deg = hist[t];
    // exclusive scan of hist
    scn[t] = deg; __syncthreads();
    for (int off = 1; off < 256; off <<= 1) {
        int u = (t >= off) ? scn[t - off] : 0;
        __syncthreads();
        scn[t] += u;
        __syncthreads();
    }
    int myoff = bbase[b] + scn[t] - deg;
    int node = b * 256 + t;
    if (node < NN) {
        cnt[node]  = deg;
        offs[node] = myoff;
        float d = 1.0f / sqrtf((float)(deg + 1));
        dinv[node] = d;
        float4 xv = ((const float4*)x)[node];
        float4 o; o.x = d * xv.x; o.y = d * xv.y; o.z = d * xv.z; o.w = d * xv.w;
        ((float4*)xs)[node] = o;
    }
    cur[t] = myoff;
    __syncthreads();
    for (int e = t; e < sz; e += 256) {
        unsigned int u = buf[e];
        int p = atomicAdd(&cur[u >> SRCBITS], 1);
        csr[p] = (int)(u & SRCMASK);
    }
}

// ---- layer-1 aggregation on raw dim-4 features -----------------------------
__global__ void k_agg1(const float* __restrict__ x, const float* __restrict__ xs,
                       const float* __restrict__ dinv, const int* __restrict__ offs,
                       const int* __restrict__ cnt, const int* __restrict__ csr,
                       float* __restrict__ agg) {
    int i = blockIdx.x * 256 + threadIdx.x;
    if (i >= NN) return;
    float sx = 0.f, sy = 0.f, sz = 0.f, sw = 0.f;
    int b = offs[i], n = cnt[i];
    for (int j = 0; j < n; ++j) {
        int s = csr[b + j];
        float4 v = ((const float4*)xs)[s];
        sx += v.x; sy += v.y; sz += v.z; sw += v.w;
    }
    float d = dinv[i];
    float4 xi = ((const float4*)x)[i];
    float4 o;
    o.x = d * (sx + d * xi.x);
    o.y = d * (sy + d * xi.y);
    o.z = d * (sz + d * xi.z);
    o.w = d * (sw + d * xi.w);
    ((float4*)agg)[i] = o;
}

// ---- h1 = relu(agg@W1 + b1); hs = dinv * (h1@W2). 4 nodes/block ------------
__global__ void k_mm(const float* __restrict__ agg, const float* __restrict__ W1,
                     const float* __restrict__ b1, const float* __restrict__ W2,
                     const float* __restrict__ dinv, float* __restrict__ hs) {
    __shared__ float sW2[64 * 64];
    __shared__ float sh1[4][64];
    int t = threadIdx.x;
#pragma unroll
    for (int r = 0; r < 16; ++r) sW2[r * 256 + t] = W2[r * 256 + t];
    int node = blockIdx.x * 4 + (t >> 6);
    int c = t & 63;
    float4 a = ((const float4*)agg)[node];
    float h = a.x * W1[c] + a.y * W1[64 + c] + a.z * W1[128 + c] + a.w * W1[192 + c];
    h = fmaxf(h + b1[c], 0.0f);
    sh1[t >> 6][c] = h;
    __syncthreads();
    const float* h1 = sh1[t >> 6];
    float sum = 0.0f;
#pragma unroll
    for (int k = 0; k < 64; ++k) sum = fmaf(h1[k], sW2[k * 64 + c], sum);
    hs[node * 64 + c] = sum * dinv[node];
}

// ---- layer-2 gather + head, fused. One wave per node. ----------------------
__global__ void k_gather_head(const float* __restrict__ hs, const int* __restrict__ offs,
                              const int* __restrict__ cnt, const int* __restrict__ csr,
                              const float* __restrict__ dinv, const float* __restrict__ b2,
                              const float* __restrict__ Wl, const float* __restrict__ bl,
                              float* __restrict__ out) {
    int t = threadIdx.x;
    int node = blockIdx.x * 4 + (t >> 6);
    int c = t & 63;
    int b = offs[node], n = cnt[node];
    float a = hs[node * 64 + c];                 // self loop (hs already *dinv[self])
    int myidx = (c < n) ? csr[b + c] : 0;        // prefetch up to 64 indices
    int m = n < 64 ? n : 64;
    for (int j = 0; j < m; ++j) {
        int s = __shfl(myidx, j, 64);
        a += hs[s * 64 + c];
    }
    for (int j = 64; j < n; ++j) {               // rare: deg > 64
        int s = csr[b + j];
        a += hs[s * 64 + c];
    }
    float h2 = fmaxf(fmaf(dinv[node], a, b2[c]), 0.0f);
    float v = h2 * Wl[c];
#pragma unroll
    for (int off = 32; off; off >>= 1) v += __shfl_down(v, off, 64);
    if (c == 0) out[node] = v + bl[0];
}

extern "C" void kernel_launch(void* const* d_in, const int* in_sizes, int n_in,
                              void* d_out, int out_size, void* d_ws, size_t ws_size,
                              hipStream_t stream) {
    const float* x  = (const float*)d_in[0];
    const int*   ei = (const int*)d_in[1];
    const float* W1 = (const float*)d_in[2];
    const float* b1 = (const float*)d_in[3];
    const float* W2 = (const float*)d_in[4];
    const float* b2 = (const float*)d_in[5];
    const float* Wl = (const float*)d_in[6];
    const float* bl = (const float*)d_in[7];
    float* out = (float*)d_out;

    char* w = (char*)d_ws;
    float* dinv  = (float*)w;                  w += NN * 4;
    int*   cnt   = (int*)w;                    w += NN * 4;
    int*   offs  = (int*)w;                    w += NN * 4;
    int*   csr   = (int*)w;                    w += NE * 4;
    float* xs    = (float*)w;                  w += NN * 4 * 4;
    float* agg   = (float*)w;                  w += NN * 4 * 4;
    float* hs    = (float*)w;                  w += NN * HID * 4;
    int*   bcur  = (int*)w;                    w += ((NBUK + 3) & ~3) * 4;
    int*   bbase = (int*)w;                    w += ((NBUK + 3) & ~3) * 4;
    unsigned int* bbuf = (unsigned int*)w;     w += (size_t)NBUK * CAP * 4;  // 9.6 MB
    int*   flag  = (int*)w;                    w += 4;   // ~46 MB total

    const int GN = (NN + 255) / 256;       // 391
    const int GE = (NE + 4095) / 4096;     // 391

    hipLaunchKernelGGL(k_init,  dim3(1),    dim3(256), 0, stream, ei, flag, bcur);
    hipLaunchKernelGGL(k_passA, dim3(GE),   dim3(256), 0, stream, ei, flag, bcur, bbuf);
    hipLaunchKernelGGL(k_scanb, dim3(1),    dim3(512), 0, stream, bcur, bbase);
    hipLaunchKernelGGL(k_passB, dim3(NBUK), dim3(256), 0, stream,
                       bbuf, bcur, bbase, x, cnt, offs, dinv, xs, csr);

    hipLaunchKernelGGL(k_agg1, dim3(GN), dim3(256), 0, stream,
                       x, xs, dinv, offs, cnt, csr, agg);
    hipLaunchKernelGGL(k_mm, dim3(NN / 4), dim3(256), 0, stream,
                       agg, W1, b1, W2, dinv, hs);
    hipLaunchKernelGGL(k_gather_head, dim3(NN / 4), dim3(256), 0, stream,
                       hs, offs, cnt, csr, dinv, b2, Wl, bl, out);
}

// Round 5
// 527.220 us; speedup vs baseline: 1.5536x; 1.5536x over previous
//
#include <hip/hip_runtime.h>

#define NN 100000
#define NE 1600000
#define HID 64
#define NBUK 391              // buckets of 256 node ids: (NN+255)/256
#define SRCBITS 17
#define SRCMASK 0x1FFFF
#define SCANN (NBUK * NBUK)   // 152881
#define SCANT 1024
#define SCANC ((SCANN + SCANT - 1) / SCANT)  // 150

// ---- detect edge dtype (int64 vs int32) ------------------------------------
__global__ void k_detect(const int* __restrict__ ei, int* __restrict__ flag) {
    int t = threadIdx.x;  // 64
    int v = ei[2 * t + 1];
    unsigned long long b = __ballot(v != 0);
    if (t == 0) *flag = (b == 0ULL) ? 1 : 0;  // 1 => int64 layout
}

__device__ __forceinline__ int ld_idx(const int* __restrict__ ei, int off, int is64) {
    return is64 ? ei[2 * off] : ei[off];
}

// ---- pass A1: per-block bucket histogram (LDS atomics only) ----------------
__global__ void k_histA(const int* __restrict__ ei, const int* __restrict__ flag,
                        int* __restrict__ histG) {
    __shared__ int hist[NBUK];
    int t = threadIdx.x;  // 256
    for (int i = t; i < NBUK; i += 256) hist[i] = 0;
    __syncthreads();
    int f = *flag;
    int base = blockIdx.x * 4096;
#pragma unroll
    for (int k = 0; k < 16; ++k) {
        int e = base + k * 256 + t;
        if (e < NE) {
            int d = ld_idx(ei, NE + e, f);
            atomicAdd(&hist[d >> 8], 1);
        }
    }
    __syncthreads();
    // bucket-major layout for the global scan
    for (int i = t; i < NBUK; i += 256) histG[i * NBUK + blockIdx.x] = hist[i];
}

// ---- exclusive scan of 152881 counts, single block -------------------------
__global__ void k_scan(int* __restrict__ g) {
    __shared__ int s[SCANT];
    int t = threadIdx.x;
    int lo = t * SCANC;
    int hi = lo + SCANC; if (hi > SCANN) hi = SCANN;
    int sum = 0;
    for (int i = lo; i < hi; ++i) sum += g[i];
    s[t] = sum; __syncthreads();
    for (int off = 1; off < SCANT; off <<= 1) {
        int u = (t >= off) ? s[t - off] : 0;
        __syncthreads();
        s[t] += u;
        __syncthreads();
    }
    int run = s[t] - sum;  // exclusive prefix for this thread's chunk
    for (int i = lo; i < hi; ++i) { int v = g[i]; g[i] = run; run += v; }
}

// ---- pass A2: place packed edges into disjoint per-(block,bucket) ranges ---
__global__ void k_fillA(const int* __restrict__ ei, const int* __restrict__ flag,
                        const int* __restrict__ histS, unsigned int* __restrict__ bbuf) {
    __shared__ int cur[NBUK];
    int t = threadIdx.x;  // 256
    for (int i = t; i < NBUK; i += 256) cur[i] = histS[i * NBUK + blockIdx.x];
    __syncthreads();
    int f = *flag;
    int base = blockIdx.x * 4096;
#pragma unroll
    for (int k = 0; k < 16; ++k) {
        int e = base + k * 256 + t;
        if (e < NE) {
            int s = ld_idx(ei, e, f);
            int d = ld_idx(ei, NE + e, f);
            int p = atomicAdd(&cur[d >> 8], 1);   // LDS atomic
            bbuf[p] = ((unsigned int)(d & 255) << SRCBITS) | (unsigned int)s;
        }
    }
}

// ---- pass B: per-bucket 256-slot sort -> cnt/offs/dinv/xs + csr ------------
__global__ void k_passB(const unsigned int* __restrict__ bbuf, const int* __restrict__ histS,
                        const float* __restrict__ x,
                        int* __restrict__ cnt, int* __restrict__ offs,
                        float* __restrict__ dinv, float* __restrict__ xs,
                        int* __restrict__ csr) {
    __shared__ int hist[256];
    __shared__ int scn[256];
    __shared__ int cur[256];
    int t = threadIdx.x;  // 256
    int b = blockIdx.x;
    int base = histS[b * NBUK];
    int next = (b == NBUK - 1) ? NE : histS[(b + 1) * NBUK];
    int sz = next - base;
    const unsigned int* buf = bbuf + base;
    hist[t] = 0;
    __syncthreads();
    for (int e = t; e < sz; e += 256)
        atomicAdd(&hist[buf[e] >> SRCBITS], 1);
    __syncthreads();
    int deg = hist[t];
    scn[t] = deg; __syncthreads();
    for (int off = 1; off < 256; off <<= 1) {
        int u = (t >= off) ? scn[t - off] : 0;
        __syncthreads();
        scn[t] += u;
        __syncthreads();
    }
    int myoff = base + scn[t] - deg;
    int node = b * 256 + t;
    if (node < NN) {
        cnt[node]  = deg;
        offs[node] = myoff;
        float d = 1.0f / sqrtf((float)(deg + 1));
        dinv[node] = d;
        float4 xv = ((const float4*)x)[node];
        float4 o; o.x = d * xv.x; o.y = d * xv.y; o.z = d * xv.z; o.w = d * xv.w;
        ((float4*)xs)[node] = o;
    }
    cur[t] = myoff;
    __syncthreads();
    for (int e = t; e < sz; e += 256) {
        unsigned int u = buf[e];
        int p = atomicAdd(&cur[u >> SRCBITS], 1);
        csr[p] = (int)(u & SRCMASK);
    }
}

// ---- layer-1 aggregation on raw dim-4 features -----------------------------
__global__ void k_agg1(const float* __restrict__ x, const float* __restrict__ xs,
                       const float* __restrict__ dinv, const int* __restrict__ offs,
                       const int* __restrict__ cnt, const int* __restrict__ csr,
                       float* __restrict__ agg) {
    int i = blockIdx.x * 256 + threadIdx.x;
    if (i >= NN) return;
    float sx = 0.f, sy = 0.f, sz = 0.f, sw = 0.f;
    int b = offs[i], n = cnt[i];
    for (int j = 0; j < n; ++j) {
        int s = csr[b + j];
        float4 v = ((const float4*)xs)[s];
        sx += v.x; sy += v.y; sz += v.z; sw += v.w;
    }
    float d = dinv[i];
    float4 xi = ((const float4*)x)[i];
    float4 o;
    o.x = d * (sx + d * xi.x);
    o.y = d * (sy + d * xi.y);
    o.z = d * (sz + d * xi.z);
    o.w = d * (sw + d * xi.w);
    ((float4*)agg)[i] = o;
}

// ---- h1 = relu(agg@W1 + b1); hs = dinv * (h1@W2). 4 nodes/block ------------
__global__ void k_mm(const float* __restrict__ agg, const float* __restrict__ W1,
                     const float* __restrict__ b1, const float* __restrict__ W2,
                     const float* __restrict__ dinv, float* __restrict__ hs) {
    __shared__ float sW2[64 * 64];
    __shared__ float sh1[4][64];
    int t = threadIdx.x;
#pragma unroll
    for (int r = 0; r < 16; ++r) sW2[r * 256 + t] = W2[r * 256 + t];
    int node = blockIdx.x * 4 + (t >> 6);
    int c = t & 63;
    float4 a = ((const float4*)agg)[node];
    float h = a.x * W1[c] + a.y * W1[64 + c] + a.z * W1[128 + c] + a.w * W1[192 + c];
    h = fmaxf(h + b1[c], 0.0f);
    sh1[t >> 6][c] = h;
    __syncthreads();
    const float* h1 = sh1[t >> 6];
    float sum = 0.0f;
#pragma unroll
    for (int k = 0; k < 64; ++k) sum = fmaf(h1[k], sW2[k * 64 + c], sum);
    hs[node * 64 + c] = sum * dinv[node];
}

// ---- layer-2 gather + head, fused. One wave per node. ----------------------
__global__ void k_gather_head(const float* __restrict__ hs, const int* __restrict__ offs,
                              const int* __restrict__ cnt, const int* __restrict__ csr,
                              const float* __restrict__ dinv, const float* __restrict__ b2,
                              const float* __restrict__ Wl, const float* __restrict__ bl,
                              float* __restrict__ out) {
    int t = threadIdx.x;
    int node = blockIdx.x * 4 + (t >> 6);
    int c = t & 63;
    int b = offs[node], n = cnt[node];
    float a = hs[node * 64 + c];                 // self loop (hs already *dinv[self])
    int myidx = (c < n) ? csr[b + c] : 0;        // prefetch up to 64 indices
    int m = n < 64 ? n : 64;
    for (int j = 0; j < m; ++j) {
        int s = __shfl(myidx, j, 64);
        a += hs[s * 64 + c];
    }
    for (int j = 64; j < n; ++j) {               // rare: deg > 64
        int s = csr[b + j];
        a += hs[s * 64 + c];
    }
    float h2 = fmaxf(fmaf(dinv[node], a, b2[c]), 0.0f);
    float v = h2 * Wl[c];
#pragma unroll
    for (int off = 32; off; off >>= 1) v += __shfl_down(v, off, 64);
    if (c == 0) out[node] = v + bl[0];
}

extern "C" void kernel_launch(void* const* d_in, const int* in_sizes, int n_in,
                              void* d_out, int out_size, void* d_ws, size_t ws_size,
                              hipStream_t stream) {
    const float* x  = (const float*)d_in[0];
    const int*   ei = (const int*)d_in[1];
    const float* W1 = (const float*)d_in[2];
    const float* b1 = (const float*)d_in[3];
    const float* W2 = (const float*)d_in[4];
    const float* b2 = (const float*)d_in[5];
    const float* Wl = (const float*)d_in[6];
    const float* bl = (const float*)d_in[7];
    float* out = (float*)d_out;

    char* w = (char*)d_ws;
    float* dinv  = (float*)w;                  w += NN * 4;
    int*   cnt   = (int*)w;                    w += NN * 4;
    int*   offs  = (int*)w;                    w += NN * 4;
    int*   csr   = (int*)w;                    w += NE * 4;
    float* xs    = (float*)w;                  w += NN * 4 * 4;
    float* agg   = (float*)w;                  w += NN * 4 * 4;
    float* hs    = (float*)w;                  w += NN * HID * 4;
    int*   histG = (int*)w;                    w += (size_t)SCANN * 4;      // 612 KB
    unsigned int* bbuf = (unsigned int*)w;     w += (size_t)NE * 4;        // 6.4 MB
    int*   flag  = (int*)w;                    w += 4;    // ~44 MB total

    const int GN = (NN + 255) / 256;       // 391
    const int GE = (NE + 4095) / 4096;     // 391

    hipLaunchKernelGGL(k_detect, dim3(1),    dim3(64),    0, stream, ei, flag);
    hipLaunchKernelGGL(k_histA,  dim3(GE),   dim3(256),   0, stream, ei, flag, histG);
    hipLaunchKernelGGL(k_scan,   dim3(1),    dim3(SCANT), 0, stream, histG);
    hipLaunchKernelGGL(k_fillA,  dim3(GE),   dim3(256),   0, stream, ei, flag, histG, bbuf);
    hipLaunchKernelGGL(k_passB,  dim3(NBUK), dim3(256),   0, stream,
                       bbuf, histG, x, cnt, offs, dinv, xs, csr);

    hipLaunchKernelGGL(k_agg1, dim3(GN), dim3(256), 0, stream,
                       x, xs, dinv, offs, cnt, csr, agg);
    hipLaunchKernelGGL(k_mm, dim3(NN / 4), dim3(256), 0, stream,
                       agg, W1, b1, W2, dinv, hs);
    hipLaunchKernelGGL(k_gather_head, dim3(NN / 4), dim3(256), 0, stream,
                       hs, offs, cnt, csr, dinv, b2, Wl, bl, out);
}

// Round 6
// 285.252 us; speedup vs baseline: 2.8714x; 1.8483x over previous
//
#include <hip/hip_runtime.h>

#define NN 100000
#define NE 1600000
#define HID 64
#define NBUK 391              // buckets of 256 node ids: (NN+255)/256
#define SRCBITS 17
#define SRCMASK 0x1FFFF
#define SCANN (NBUK * NBUK)   // 152881
#define CHUNK 1024
#define NCH ((SCANN + CHUNK - 1) / CHUNK)   // 150 chunks

// ---- detect edge dtype (int64 vs int32) ------------------------------------
__global__ void k_detect(const int* __restrict__ ei, int* __restrict__ flag) {
    int t = threadIdx.x;  // 64
    int v = ei[2 * t + 1];
    unsigned long long b = __ballot(v != 0);
    if (t == 0) *flag = (b == 0ULL) ? 1 : 0;  // 1 => int64 layout
}

__device__ __forceinline__ int ld_idx(const int* __restrict__ ei, int off, int is64) {
    return is64 ? ei[2 * off] : ei[off];
}

// ---- pass A1: per-block bucket histogram (LDS atomics only) ----------------
__global__ void k_histA(const int* __restrict__ ei, const int* __restrict__ flag,
                        int* __restrict__ histG) {
    __shared__ int hist[NBUK];
    int t = threadIdx.x;  // 256
    for (int i = t; i < NBUK; i += 256) hist[i] = 0;
    __syncthreads();
    int f = *flag;
    int base = blockIdx.x * 4096;
#pragma unroll
    for (int k = 0; k < 16; ++k) {
        int e = base + k * 256 + t;
        if (e < NE) {
            int d = ld_idx(ei, NE + e, f);
            atomicAdd(&hist[d >> 8], 1);
        }
    }
    __syncthreads();
    // bucket-major layout for the global scan
    for (int i = t; i < NBUK; i += 256) histG[i * NBUK + blockIdx.x] = hist[i];
}

// ---- 3-stage exclusive scan of SCANN counts --------------------------------
// stage 1: per-chunk exclusive scan (int4 vectorized) + chunk totals
__global__ void k_scan1(int* __restrict__ g, int* __restrict__ bsum) {
    __shared__ int s[256];
    int t = threadIdx.x;
    int i4 = blockIdx.x * 256 + t;
    int base = i4 * 4;
    int4 v = make_int4(0, 0, 0, 0);
    if (base + 3 < SCANN) v = ((const int4*)g)[i4];
    else {
        if (base + 0 < SCANN) v.x = g[base + 0];
        if (base + 1 < SCANN) v.y = g[base + 1];
        if (base + 2 < SCANN) v.z = g[base + 2];
        if (base + 3 < SCANN) v.w = g[base + 3];
    }
    int tsum = v.x + v.y + v.z + v.w;
    s[t] = tsum; __syncthreads();
    for (int off = 1; off < 256; off <<= 1) {
        int u = (t >= off) ? s[t - off] : 0;
        __syncthreads();
        s[t] += u;
        __syncthreads();
    }
    int run = s[t] - tsum;                 // exclusive prefix for this thread
    int4 o;
    o.x = run;           run += v.x;
    o.y = run;           run += v.y;
    o.z = run;           run += v.z;
    o.w = run;
    if (base + 3 < SCANN) ((int4*)g)[i4] = o;
    else {
        if (base + 0 < SCANN) g[base + 0] = o.x;
        if (base + 1 < SCANN) g[base + 1] = o.y;
        if (base + 2 < SCANN) g[base + 2] = o.z;
        if (base + 3 < SCANN) g[base + 3] = o.w;
    }
    if (t == 255) bsum[blockIdx.x] = s[255];
}

// stage 2: scan the NCH chunk totals (one small block)
__global__ void k_scan2(int* __restrict__ bsum) {
    __shared__ int s[256];
    int t = threadIdx.x;
    int v = (t < NCH) ? bsum[t] : 0;
    s[t] = v; __syncthreads();
    for (int off = 1; off < 256; off <<= 1) {
        int u = (t >= off) ? s[t - off] : 0;
        __syncthreads();
        s[t] += u;
        __syncthreads();
    }
    if (t < NCH) bsum[t] = s[t] - v;       // exclusive
}

// stage 3: add chunk prefix
__global__ void k_scan3(int* __restrict__ g, const int* __restrict__ bsum) {
    int t = threadIdx.x;
    int i4 = blockIdx.x * 256 + t;
    int base = i4 * 4;
    int add = bsum[blockIdx.x];
    if (base + 3 < SCANN) {
        int4 v = ((const int4*)g)[i4];
        v.x += add; v.y += add; v.z += add; v.w += add;
        ((int4*)g)[i4] = v;
    } else {
        if (base + 0 < SCANN) g[base + 0] += add;
        if (base + 1 < SCANN) g[base + 1] += add;
        if (base + 2 < SCANN) g[base + 2] += add;
        if (base + 3 < SCANN) g[base + 3] += add;
    }
}

// ---- pass A2: place packed edges into disjoint per-(block,bucket) ranges ---
__global__ void k_fillA(const int* __restrict__ ei, const int* __restrict__ flag,
                        const int* __restrict__ histS, unsigned int* __restrict__ bbuf) {
    __shared__ int cur[NBUK];
    int t = threadIdx.x;  // 256
    for (int i = t; i < NBUK; i += 256) cur[i] = histS[i * NBUK + blockIdx.x];
    __syncthreads();
    int f = *flag;
    int base = blockIdx.x * 4096;
#pragma unroll
    for (int k = 0; k < 16; ++k) {
        int e = base + k * 256 + t;
        if (e < NE) {
            int s = ld_idx(ei, e, f);
            int d = ld_idx(ei, NE + e, f);
            int p = atomicAdd(&cur[d >> 8], 1);   // LDS atomic
            bbuf[p] = ((unsigned int)(d & 255) << SRCBITS) | (unsigned int)s;
        }
    }
}

// ---- pass B: per-bucket 256-slot sort -> cnt/offs/dinv/xs + csr ------------
__global__ void k_passB(const unsigned int* __restrict__ bbuf, const int* __restrict__ histS,
                        const float* __restrict__ x,
                        int* __restrict__ cnt, int* __restrict__ offs,
                        float* __restrict__ dinv, float* __restrict__ xs,
                        int* __restrict__ csr) {
    __shared__ int hist[256];
    __shared__ int scn[256];
    __shared__ int cur[256];
    int t = threadIdx.x;  // 256
    int b = blockIdx.x;
    int base = histS[b * NBUK];
    int next = (b == NBUK - 1) ? NE : histS[(b + 1) * NBUK];
    int sz = next - base;
    const unsigned int* buf = bbuf + base;
    hist[t] = 0;
    __syncthreads();
    for (int e = t; e < sz; e += 256)
        atomicAdd(&hist[buf[e] >> SRCBITS], 1);
    __syncthreads();
    int deg = hist[t];
    scn[t] = deg; __syncthreads();
    for (int off = 1; off < 256; off <<= 1) {
        int u = (t >= off) ? scn[t - off] : 0;
        __syncthreads();
        scn[t] += u;
        __syncthreads();
    }
    int myoff = base + scn[t] - deg;
    int node = b * 256 + t;
    if (node < NN) {
        cnt[node]  = deg;
        offs[node] = myoff;
        float d = 1.0f / sqrtf((float)(deg + 1));
        dinv[node] = d;
        float4 xv = ((const float4*)x)[node];
        float4 o; o.x = d * xv.x; o.y = d * xv.y; o.z = d * xv.z; o.w = d * xv.w;
        ((float4*)xs)[node] = o;
    }
    cur[t] = myoff;
    __syncthreads();
    for (int e = t; e < sz; e += 256) {
        unsigned int u = buf[e];
        int p = atomicAdd(&cur[u >> SRCBITS], 1);
        csr[p] = (int)(u & SRCMASK);
    }
}

// ---- layer-1 aggregation on raw dim-4 features -----------------------------
__global__ void k_agg1(const float* __restrict__ x, const float* __restrict__ xs,
                       const float* __restrict__ dinv, const int* __restrict__ offs,
                       const int* __restrict__ cnt, const int* __restrict__ csr,
                       float* __restrict__ agg) {
    int i = blockIdx.x * 256 + threadIdx.x;
    if (i >= NN) return;
    float sx = 0.f, sy = 0.f, sz = 0.f, sw = 0.f;
    int b = offs[i], n = cnt[i];
    for (int j = 0; j < n; ++j) {
        int s = csr[b + j];
        float4 v = ((const float4*)xs)[s];
        sx += v.x; sy += v.y; sz += v.z; sw += v.w;
    }
    float d = dinv[i];
    float4 xi = ((const float4*)x)[i];
    float4 o;
    o.x = d * (sx + d * xi.x);
    o.y = d * (sy + d * xi.y);
    o.z = d * (sz + d * xi.z);
    o.w = d * (sw + d * xi.w);
    ((float4*)agg)[i] = o;
}

// ---- h1 = relu(agg@W1 + b1); hs = dinv * (h1@W2). 4 nodes/block ------------
__global__ void k_mm(const float* __restrict__ agg, const float* __restrict__ W1,
                     const float* __restrict__ b1, const float* __restrict__ W2,
                     const float* __restrict__ dinv, float* __restrict__ hs) {
    __shared__ float sW2[64 * 64];
    __shared__ float sh1[4][64];
    int t = threadIdx.x;
#pragma unroll
    for (int r = 0; r < 16; ++r) sW2[r * 256 + t] = W2[r * 256 + t];
    int node = blockIdx.x * 4 + (t >> 6);
    int c = t & 63;
    float4 a = ((const float4*)agg)[node];
    float h = a.x * W1[c] + a.y * W1[64 + c] + a.z * W1[128 + c] + a.w * W1[192 + c];
    h = fmaxf(h + b1[c], 0.0f);
    sh1[t >> 6][c] = h;
    __syncthreads();
    const float* h1 = sh1[t >> 6];
    float sum = 0.0f;
#pragma unroll
    for (int k = 0; k < 64; ++k) sum = fmaf(h1[k], sW2[k * 64 + c], sum);
    hs[node * 64 + c] = sum * dinv[node];
}

// ---- layer-2 gather + head, fused. One wave per node. ----------------------
__global__ void k_gather_head(const float* __restrict__ hs, const int* __restrict__ offs,
                              const int* __restrict__ cnt, const int* __restrict__ csr,
                              const float* __restrict__ dinv, const float* __restrict__ b2,
                              const float* __restrict__ Wl, const float* __restrict__ bl,
                              float* __restrict__ out) {
    int t = threadIdx.x;
    int node = blockIdx.x * 4 + (t >> 6);
    int c = t & 63;
    int b = offs[node], n = cnt[node];
    float a = hs[node * 64 + c];                 // self loop (hs already *dinv[self])
    int myidx = (c < n) ? csr[b + c] : 0;        // prefetch up to 64 indices
    int m = n < 64 ? n : 64;
    for (int j = 0; j < m; ++j) {
        int s = __shfl(myidx, j, 64);
        a += hs[s * 64 + c];
    }
    for (int j = 64; j < n; ++j) {               // rare: deg > 64
        int s = csr[b + j];
        a += hs[s * 64 + c];
    }
    float h2 = fmaxf(fmaf(dinv[node], a, b2[c]), 0.0f);
    float v = h2 * Wl[c];
#pragma unroll
    for (int off = 32; off; off >>= 1) v += __shfl_down(v, off, 64);
    if (c == 0) out[node] = v + bl[0];
}

extern "C" void kernel_launch(void* const* d_in, const int* in_sizes, int n_in,
                              void* d_out, int out_size, void* d_ws, size_t ws_size,
                              hipStream_t stream) {
    const float* x  = (const float*)d_in[0];
    const int*   ei = (const int*)d_in[1];
    const float* W1 = (const float*)d_in[2];
    const float* b1 = (const float*)d_in[3];
    const float* W2 = (const float*)d_in[4];
    const float* b2 = (const float*)d_in[5];
    const float* Wl = (const float*)d_in[6];
    const float* bl = (const float*)d_in[7];
    float* out = (float*)d_out;

    char* w = (char*)d_ws;
    float* dinv  = (float*)w;                  w += NN * 4;
    int*   cnt   = (int*)w;                    w += NN * 4;
    int*   offs  = (int*)w;                    w += NN * 4;
    int*   csr   = (int*)w;                    w += NE * 4;
    float* xs    = (float*)w;                  w += NN * 4 * 4;
    float* agg   = (float*)w;                  w += NN * 4 * 4;
    float* hs    = (float*)w;                  w += NN * HID * 4;
    int*   histG = (int*)w;                    w += (size_t)((SCANN + 3) & ~3) * 4;  // 612 KB
    int*   bsum  = (int*)w;                    w += 256 * 4;
    unsigned int* bbuf = (unsigned int*)w;     w += (size_t)NE * 4;                  // 6.4 MB
    int*   flag  = (int*)w;                    w += 4;    // ~44 MB total

    const int GN = (NN + 255) / 256;       // 391
    const int GE = (NE + 4095) / 4096;     // 391

    hipLaunchKernelGGL(k_detect, dim3(1),    dim3(64),  0, stream, ei, flag);
    hipLaunchKernelGGL(k_histA,  dim3(GE),   dim3(256), 0, stream, ei, flag, histG);
    hipLaunchKernelGGL(k_scan1,  dim3(NCH),  dim3(256), 0, stream, histG, bsum);
    hipLaunchKernelGGL(k_scan2,  dim3(1),    dim3(256), 0, stream, bsum);
    hipLaunchKernelGGL(k_scan3,  dim3(NCH),  dim3(256), 0, stream, histG, bsum);
    hipLaunchKernelGGL(k_fillA,  dim3(GE),   dim3(256), 0, stream, ei, flag, histG, bbuf);
    hipLaunchKernelGGL(k_passB,  dim3(NBUK), dim3(256), 0, stream,
                       bbuf, histG, x, cnt, offs, dinv, xs, csr);

    hipLaunchKernelGGL(k_agg1, dim3(GN), dim3(256), 0, stream,
                       x, xs, dinv, offs, cnt, csr, agg);
    hipLaunchKernelGGL(k_mm, dim3(NN / 4), dim3(256), 0, stream,
                       agg, W1, b1, W2, dinv, hs);
    hipLaunchKernelGGL(k_gather_head, dim3(NN / 4), dim3(256), 0, stream,
                       hs, offs, cnt, csr, dinv, b2, Wl, bl, out);
}

// Round 7
// 238.612 us; speedup vs baseline: 3.4326x; 1.1955x over previous
//
#include <hip/hip_runtime.h>

#define NN 100000
#define NE 1600000
#define HID 64
#define NBUK 391              // buckets of 256 node ids: (NN+255)/256
#define SRCBITS 17
#define SRCMASK 0x1FFFF
#define SCANN (NBUK * NBUK)   // 152881
#define CHUNK 1024
#define NCH ((SCANN + CHUNK - 1) / CHUNK)   // 150 chunks

// ---- detect edge dtype (int64 vs int32) ------------------------------------
__global__ void k_detect(const int* __restrict__ ei, int* __restrict__ flag) {
    int t = threadIdx.x;  // 64
    int v = ei[2 * t + 1];
    unsigned long long b = __ballot(v != 0);
    if (t == 0) *flag = (b == 0ULL) ? 1 : 0;  // 1 => int64 layout
}

__device__ __forceinline__ int ld_idx(const int* __restrict__ ei, int off, int is64) {
    return is64 ? ei[2 * off] : ei[off];
}

// ---- pass A1: per-block bucket histogram (LDS atomics only) ----------------
__global__ void k_histA(const int* __restrict__ ei, const int* __restrict__ flag,
                        int* __restrict__ histG) {
    __shared__ int hist[NBUK];
    int t = threadIdx.x;  // 256
    for (int i = t; i < NBUK; i += 256) hist[i] = 0;
    __syncthreads();
    int f = *flag;
    int base = blockIdx.x * 4096;
#pragma unroll
    for (int k = 0; k < 16; ++k) {
        int e = base + k * 256 + t;
        if (e < NE) {
            int d = ld_idx(ei, NE + e, f);
            atomicAdd(&hist[d >> 8], 1);
        }
    }
    __syncthreads();
    for (int i = t; i < NBUK; i += 256) histG[i * NBUK + blockIdx.x] = hist[i];
}

// ---- 3-stage exclusive scan of SCANN counts --------------------------------
__global__ void k_scan1(int* __restrict__ g, int* __restrict__ bsum) {
    __shared__ int s[256];
    int t = threadIdx.x;
    int i4 = blockIdx.x * 256 + t;
    int base = i4 * 4;
    int4 v = make_int4(0, 0, 0, 0);
    if (base + 3 < SCANN) v = ((const int4*)g)[i4];
    else {
        if (base + 0 < SCANN) v.x = g[base + 0];
        if (base + 1 < SCANN) v.y = g[base + 1];
        if (base + 2 < SCANN) v.z = g[base + 2];
        if (base + 3 < SCANN) v.w = g[base + 3];
    }
    int tsum = v.x + v.y + v.z + v.w;
    s[t] = tsum; __syncthreads();
    for (int off = 1; off < 256; off <<= 1) {
        int u = (t >= off) ? s[t - off] : 0;
        __syncthreads();
        s[t] += u;
        __syncthreads();
    }
    int run = s[t] - tsum;
    int4 o;
    o.x = run; run += v.x;
    o.y = run; run += v.y;
    o.z = run; run += v.z;
    o.w = run;
    if (base + 3 < SCANN) ((int4*)g)[i4] = o;
    else {
        if (base + 0 < SCANN) g[base + 0] = o.x;
        if (base + 1 < SCANN) g[base + 1] = o.y;
        if (base + 2 < SCANN) g[base + 2] = o.z;
        if (base + 3 < SCANN) g[base + 3] = o.w;
    }
    if (t == 255) bsum[blockIdx.x] = s[255];
}

__global__ void k_scan2(int* __restrict__ bsum) {
    __shared__ int s[256];
    int t = threadIdx.x;
    int v = (t < NCH) ? bsum[t] : 0;
    s[t] = v; __syncthreads();
    for (int off = 1; off < 256; off <<= 1) {
        int u = (t >= off) ? s[t - off] : 0;
        __syncthreads();
        s[t] += u;
        __syncthreads();
    }
    if (t < NCH) bsum[t] = s[t] - v;
}

__global__ void k_scan3(int* __restrict__ g, const int* __restrict__ bsum) {
    int t = threadIdx.x;
    int i4 = blockIdx.x * 256 + t;
    int base = i4 * 4;
    int add = bsum[blockIdx.x];
    if (base + 3 < SCANN) {
        int4 v = ((const int4*)g)[i4];
        v.x += add; v.y += add; v.z += add; v.w += add;
        ((int4*)g)[i4] = v;
    } else {
        if (base + 0 < SCANN) g[base + 0] += add;
        if (base + 1 < SCANN) g[base + 1] += add;
        if (base + 2 < SCANN) g[base + 2] += add;
        if (base + 3 < SCANN) g[base + 3] += add;
    }
}

// ---- pass A2: place packed edges into disjoint per-(block,bucket) ranges ---
__global__ void k_fillA(const int* __restrict__ ei, const int* __restrict__ flag,
                        const int* __restrict__ histS, unsigned int* __restrict__ bbuf) {
    __shared__ int cur[NBUK];
    int t = threadIdx.x;  // 256
    for (int i = t; i < NBUK; i += 256) cur[i] = histS[i * NBUK + blockIdx.x];
    __syncthreads();
    int f = *flag;
    int base = blockIdx.x * 4096;
#pragma unroll
    for (int k = 0; k < 16; ++k) {
        int e = base + k * 256 + t;
        if (e < NE) {
            int s = ld_idx(ei, e, f);
            int d = ld_idx(ei, NE + e, f);
            int p = atomicAdd(&cur[d >> 8], 1);   // LDS atomic
            bbuf[p] = ((unsigned int)(d & 255) << SRCBITS) | (unsigned int)s;
        }
    }
}

// ---- pass B: per-bucket 256-slot sort -> cnt/offs/dinv/xs + csr ------------
__global__ void k_passB(const unsigned int* __restrict__ bbuf, const int* __restrict__ histS,
                        const float* __restrict__ x,
                        int* __restrict__ cnt, int* __restrict__ offs,
                        float* __restrict__ dinv, float* __restrict__ xs,
                        int* __restrict__ csr) {
    __shared__ int hist[256];
    __shared__ int scn[256];
    __shared__ int cur[256];
    int t = threadIdx.x;  // 256
    int b = blockIdx.x;
    int base = histS[b * NBUK];
    int next = (b == NBUK - 1) ? NE : histS[(b + 1) * NBUK];
    int sz = next - base;
    const unsigned int* buf = bbuf + base;
    hist[t] = 0;
    __syncthreads();
    for (int e = t; e < sz; e += 256)
        atomicAdd(&hist[buf[e] >> SRCBITS], 1);
    __syncthreads();
    int deg = hist[t];
    scn[t] = deg; __syncthreads();
    for (int off = 1; off < 256; off <<= 1) {
        int u = (t >= off) ? scn[t - off] : 0;
        __syncthreads();
        scn[t] += u;
        __syncthreads();
    }
    int myoff = base + scn[t] - deg;
    int node = b * 256 + t;
    if (node < NN) {
        cnt[node]  = deg;
        offs[node] = myoff;
        float d = 1.0f / sqrtf((float)(deg + 1));
        dinv[node] = d;
        float4 xv = ((const float4*)x)[node];
        float4 o; o.x = d * xv.x; o.y = d * xv.y; o.z = d * xv.z; o.w = d * xv.w;
        ((float4*)xs)[node] = o;
    }
    cur[t] = myoff;
    __syncthreads();
    for (int e = t; e < sz; e += 256) {
        unsigned int u = buf[e];
        int p = atomicAdd(&cur[u >> SRCBITS], 1);
        csr[p] = (int)(u & SRCMASK);
    }
}

// ---- layer-1 aggregation, 8-way ILP ----------------------------------------
__global__ void k_agg1(const float* __restrict__ x, const float* __restrict__ xs,
                       const float* __restrict__ dinv, const int* __restrict__ offs,
                       const int* __restrict__ cnt, const int* __restrict__ csr,
                       float* __restrict__ agg) {
    int i = blockIdx.x * 256 + threadIdx.x;
    if (i >= NN) return;
    float sx = 0.f, sy = 0.f, sz = 0.f, sw = 0.f;
    int b = offs[i], n = cnt[i];
    int j = 0;
    for (; j + 8 <= n; j += 8) {
        int s0 = csr[b + j + 0], s1 = csr[b + j + 1], s2 = csr[b + j + 2], s3 = csr[b + j + 3];
        int s4 = csr[b + j + 4], s5 = csr[b + j + 5], s6 = csr[b + j + 6], s7 = csr[b + j + 7];
        float4 v0 = ((const float4*)xs)[s0];
        float4 v1 = ((const float4*)xs)[s1];
        float4 v2 = ((const float4*)xs)[s2];
        float4 v3 = ((const float4*)xs)[s3];
        float4 v4 = ((const float4*)xs)[s4];
        float4 v5 = ((const float4*)xs)[s5];
        float4 v6 = ((const float4*)xs)[s6];
        float4 v7 = ((const float4*)xs)[s7];
        sx += v0.x + v1.x + v2.x + v3.x + v4.x + v5.x + v6.x + v7.x;
        sy += v0.y + v1.y + v2.y + v3.y + v4.y + v5.y + v6.y + v7.y;
        sz += v0.z + v1.z + v2.z + v3.z + v4.z + v5.z + v6.z + v7.z;
        sw += v0.w + v1.w + v2.w + v3.w + v4.w + v5.w + v6.w + v7.w;
    }
    for (; j < n; ++j) {
        int s = csr[b + j];
        float4 v = ((const float4*)xs)[s];
        sx += v.x; sy += v.y; sz += v.z; sw += v.w;
    }
    float d = dinv[i];
    float4 xi = ((const float4*)x)[i];
    float4 o;
    o.x = d * (sx + d * xi.x);
    o.y = d * (sy + d * xi.y);
    o.z = d * (sz + d * xi.z);
    o.w = d * (sw + d * xi.w);
    ((float4*)agg)[i] = o;
}

// ---- h1 = relu(agg@W1 + b1); hs = dinv * (h1@W2). 4 nodes/block ------------
__global__ void k_mm(const float* __restrict__ agg, const float* __restrict__ W1,
                     const float* __restrict__ b1, const float* __restrict__ W2,
                     const float* __restrict__ dinv, float* __restrict__ hs) {
    __shared__ float sW2[64 * 64];
    __shared__ float sh1[4][64];
    int t = threadIdx.x;
#pragma unroll
    for (int r = 0; r < 16; ++r) sW2[r * 256 + t] = W2[r * 256 + t];
    int node = blockIdx.x * 4 + (t >> 6);
    int c = t & 63;
    float4 a = ((const float4*)agg)[node];
    float h = a.x * W1[c] + a.y * W1[64 + c] + a.z * W1[128 + c] + a.w * W1[192 + c];
    h = fmaxf(h + b1[c], 0.0f);
    sh1[t >> 6][c] = h;
    __syncthreads();
    const float* h1 = sh1[t >> 6];
    float sum = 0.0f;
#pragma unroll
    for (int k = 0; k < 64; ++k) sum = fmaf(h1[k], sW2[k * 64 + c], sum);
    hs[node * 64 + c] = sum * dinv[node];
}

// ---- layer-2 gather + head, fused, 8-way ILP. One wave per node. -----------
__global__ void k_gather_head(const float* __restrict__ hs, const int* __restrict__ offs,
                              const int* __restrict__ cnt, const int* __restrict__ csr,
                              const float* __restrict__ dinv, const float* __restrict__ b2,
                              const float* __restrict__ Wl, const float* __restrict__ bl,
                              float* __restrict__ out) {
    int t = threadIdx.x;
    int node = blockIdx.x * 4 + (t >> 6);
    int c = t & 63;
    int b = offs[node], n = cnt[node];
    const float* hc = hs + c;
    float a = hc[node * 64];                     // self loop (hs already *dinv[self])
    int myidx = (c < n) ? csr[b + c] : 0;        // prefetch up to 64 indices
    int m = n < 64 ? n : 64;
    int j = 0;
    float a0 = 0.f, a1 = 0.f, a2 = 0.f, a3 = 0.f;
    float a4 = 0.f, a5 = 0.f, a6 = 0.f, a7 = 0.f;
    for (; j + 8 <= m; j += 8) {
        int s0 = __shfl(myidx, j + 0, 64), s1 = __shfl(myidx, j + 1, 64);
        int s2 = __shfl(myidx, j + 2, 64), s3 = __shfl(myidx, j + 3, 64);
        int s4 = __shfl(myidx, j + 4, 64), s5 = __shfl(myidx, j + 5, 64);
        int s6 = __shfl(myidx, j + 6, 64), s7 = __shfl(myidx, j + 7, 64);
        float v0 = hc[s0 * 64], v1 = hc[s1 * 64], v2 = hc[s2 * 64], v3 = hc[s3 * 64];
        float v4 = hc[s4 * 64], v5 = hc[s5 * 64], v6 = hc[s6 * 64], v7 = hc[s7 * 64];
        a0 += v0; a1 += v1; a2 += v2; a3 += v3;
        a4 += v4; a5 += v5; a6 += v6; a7 += v7;
    }
    for (; j < m; ++j) {
        int s = __shfl(myidx, j, 64);
        a += hc[s * 64];
    }
    for (j = 64; j < n; ++j) {                   // rare: deg > 64
        int s = csr[b + j];
        a += hc[s * 64];
    }
    a += ((a0 + a1) + (a2 + a3)) + ((a4 + a5) + (a6 + a7));
    float h2 = fmaxf(fmaf(dinv[node], a, b2[c]), 0.0f);
    float v = h2 * Wl[c];
#pragma unroll
    for (int off = 32; off; off >>= 1) v += __shfl_down(v, off, 64);
    if (c == 0) out[node] = v + bl[0];
}

extern "C" void kernel_launch(void* const* d_in, const int* in_sizes, int n_in,
                              void* d_out, int out_size, void* d_ws, size_t ws_size,
                              hipStream_t stream) {
    const float* x  = (const float*)d_in[0];
    const int*   ei = (const int*)d_in[1];
    const float* W1 = (const float*)d_in[2];
    const float* b1 = (const float*)d_in[3];
    const float* W2 = (const float*)d_in[4];
    const float* b2 = (const float*)d_in[5];
    const float* Wl = (const float*)d_in[6];
    const float* bl = (const float*)d_in[7];
    float* out = (float*)d_out;

    char* w = (char*)d_ws;
    float* dinv  = (float*)w;                  w += NN * 4;
    int*   cnt   = (int*)w;                    w += NN * 4;
    int*   offs  = (int*)w;                    w += NN * 4;
    int*   csr   = (int*)w;                    w += NE * 4;
    float* xs    = (float*)w;                  w += NN * 4 * 4;
    float* agg   = (float*)w;                  w += NN * 4 * 4;
    float* hs    = (float*)w;                  w += NN * HID * 4;
    int*   histG = (int*)w;                    w += (size_t)((SCANN + 3) & ~3) * 4;  // 612 KB
    int*   bsum  = (int*)w;                    w += 256 * 4;
    unsigned int* bbuf = (unsigned int*)w;     w += (size_t)NE * 4;                  // 6.4 MB
    int*   flag  = (int*)w;                    w += 4;    // ~44 MB total

    const int GN = (NN + 255) / 256;       // 391
    const int GE = (NE + 4095) / 4096;     // 391

    hipLaunchKernelGGL(k_detect, dim3(1),    dim3(64),  0, stream, ei, flag);
    hipLaunchKernelGGL(k_histA,  dim3(GE),   dim3(256), 0, stream, ei, flag, histG);
    hipLaunchKernelGGL(k_scan1,  dim3(NCH),  dim3(256), 0, stream, histG, bsum);
    hipLaunchKernelGGL(k_scan2,  dim3(1),    dim3(256), 0, stream, bsum);
    hipLaunchKernelGGL(k_scan3,  dim3(NCH),  dim3(256), 0, stream, histG, bsum);
    hipLaunchKernelGGL(k_fillA,  dim3(GE),   dim3(256), 0, stream, ei, flag, histG, bbuf);
    hipLaunchKernelGGL(k_passB,  dim3(NBUK), dim3(256), 0, stream,
                       bbuf, histG, x, cnt, offs, dinv, xs, csr);

    hipLaunchKernelGGL(k_agg1, dim3(GN), dim3(256), 0, stream,
                       x, xs, dinv, offs, cnt, csr, agg);
    hipLaunchKernelGGL(k_mm, dim3(NN / 4), dim3(256), 0, stream,
                       agg, W1, b1, W2, dinv, hs);
    hipLaunchKernelGGL(k_gather_head, dim3(NN / 4), dim3(256), 0, stream,
                       hs, offs, cnt, csr, dinv, b2, Wl, bl, out);
}

// Round 8
// 235.871 us; speedup vs baseline: 3.4725x; 1.0116x over previous
//
#include <hip/hip_runtime.h>

#define NN 100000
#define NE 1600000
#define HID 64
#define NBUK 391              // buckets of 256 node ids: (NN+255)/256
#define SRCBITS 17
#define SRCMASK 0x1FFFF
#define EBLK 2048             // edges per histogram/fill block
#define GE2 ((NE + EBLK - 1) / EBLK)        // 782 edge-blocks
#define SCANN (NBUK * GE2)    // 305,762
#define CHUNK 1024
#define NCH ((SCANN + CHUNK - 1) / CHUNK)   // 299 chunks

__device__ __forceinline__ float bf2f(unsigned short u) {
    return __uint_as_float(((unsigned int)u) << 16);
}
__device__ __forceinline__ unsigned short f2bf(float f) {   // RTNE
    unsigned int x = __float_as_uint(f);
    return (unsigned short)((x + 0x7FFFu + ((x >> 16) & 1u)) >> 16);
}

// ---- detect edge dtype (int64 vs int32) ------------------------------------
__global__ void k_detect(const int* __restrict__ ei, int* __restrict__ flag) {
    int t = threadIdx.x;  // 64
    int v = ei[2 * t + 1];
    unsigned long long b = __ballot(v != 0);
    if (t == 0) *flag = (b == 0ULL) ? 1 : 0;  // 1 => int64 layout
}

__device__ __forceinline__ int ld_idx(const int* __restrict__ ei, int off, int is64) {
    return is64 ? ei[2 * off] : ei[off];
}

// ---- pass A1: per-block bucket histogram (LDS atomics only) ----------------
__global__ void k_histA(const int* __restrict__ ei, const int* __restrict__ flag,
                        int* __restrict__ histG) {
    __shared__ int hist[NBUK];
    int t = threadIdx.x;  // 256
    for (int i = t; i < NBUK; i += 256) hist[i] = 0;
    __syncthreads();
    int f = *flag;
    int base = blockIdx.x * EBLK;
#pragma unroll
    for (int k = 0; k < EBLK / 256; ++k) {
        int e = base + k * 256 + t;
        if (e < NE) {
            int d = ld_idx(ei, NE + e, f);
            atomicAdd(&hist[d >> 8], 1);
        }
    }
    __syncthreads();
    for (int i = t; i < NBUK; i += 256) histG[i * GE2 + blockIdx.x] = hist[i];
}

// ---- 3-stage exclusive scan of SCANN counts --------------------------------
__global__ void k_scan1(int* __restrict__ g, int* __restrict__ bsum) {
    __shared__ int s[256];
    int t = threadIdx.x;
    int i4 = blockIdx.x * 256 + t;
    int base = i4 * 4;
    int4 v = make_int4(0, 0, 0, 0);
    if (base + 3 < SCANN) v = ((const int4*)g)[i4];
    else {
        if (base + 0 < SCANN) v.x = g[base + 0];
        if (base + 1 < SCANN) v.y = g[base + 1];
        if (base + 2 < SCANN) v.z = g[base + 2];
        if (base + 3 < SCANN) v.w = g[base + 3];
    }
    int tsum = v.x + v.y + v.z + v.w;
    s[t] = tsum; __syncthreads();
    for (int off = 1; off < 256; off <<= 1) {
        int u = (t >= off) ? s[t - off] : 0;
        __syncthreads();
        s[t] += u;
        __syncthreads();
    }
    int run = s[t] - tsum;
    int4 o;
    o.x = run; run += v.x;
    o.y = run; run += v.y;
    o.z = run; run += v.z;
    o.w = run;
    if (base + 3 < SCANN) ((int4*)g)[i4] = o;
    else {
        if (base + 0 < SCANN) g[base + 0] = o.x;
        if (base + 1 < SCANN) g[base + 1] = o.y;
        if (base + 2 < SCANN) g[base + 2] = o.z;
        if (base + 3 < SCANN) g[base + 3] = o.w;
    }
    if (t == 255) bsum[blockIdx.x] = s[255];
}

__global__ void k_scan2(int* __restrict__ bsum) {
    __shared__ int s[512];
    int t = threadIdx.x;  // 512
    int v = (t < NCH) ? bsum[t] : 0;
    s[t] = v; __syncthreads();
    for (int off = 1; off < 512; off <<= 1) {
        int u = (t >= off) ? s[t - off] : 0;
        __syncthreads();
        s[t] += u;
        __syncthreads();
    }
    if (t < NCH) bsum[t] = s[t] - v;
}

__global__ void k_scan3(int* __restrict__ g, const int* __restrict__ bsum) {
    int t = threadIdx.x;
    int i4 = blockIdx.x * 256 + t;
    int base = i4 * 4;
    int add = bsum[blockIdx.x];
    if (base + 3 < SCANN) {
        int4 v = ((const int4*)g)[i4];
        v.x += add; v.y += add; v.z += add; v.w += add;
        ((int4*)g)[i4] = v;
    } else {
        if (base + 0 < SCANN) g[base + 0] += add;
        if (base + 1 < SCANN) g[base + 1] += add;
        if (base + 2 < SCANN) g[base + 2] += add;
        if (base + 3 < SCANN) g[base + 3] += add;
    }
}

// ---- pass A2: place packed edges into disjoint per-(block,bucket) ranges ---
__global__ void k_fillA(const int* __restrict__ ei, const int* __restrict__ flag,
                        const int* __restrict__ histS, unsigned int* __restrict__ bbuf) {
    __shared__ int cur[NBUK];
    int t = threadIdx.x;  // 256
    for (int i = t; i < NBUK; i += 256) cur[i] = histS[i * GE2 + blockIdx.x];
    __syncthreads();
    int f = *flag;
    int base = blockIdx.x * EBLK;
#pragma unroll
    for (int k = 0; k < EBLK / 256; ++k) {
        int e = base + k * 256 + t;
        if (e < NE) {
            int s = ld_idx(ei, e, f);
            int d = ld_idx(ei, NE + e, f);
            int p = atomicAdd(&cur[d >> 8], 1);   // LDS atomic
            bbuf[p] = ((unsigned int)(d & 255) << SRCBITS) | (unsigned int)s;
        }
    }
}

// ---- pass B: per-bucket 256-slot sort -> cnt/offs/dinv/xs + csr ------------
__global__ void k_passB(const unsigned int* __restrict__ bbuf, const int* __restrict__ histS,
                        const float* __restrict__ x,
                        int* __restrict__ cnt, int* __restrict__ offs,
                        float* __restrict__ dinv, float* __restrict__ xs,
                        int* __restrict__ csr) {
    __shared__ int hist[256];
    __shared__ int scn[256];
    __shared__ int cur[256];
    int t = threadIdx.x;  // 256
    int b = blockIdx.x;
    int base = histS[b * GE2];
    int next = (b == NBUK - 1) ? NE : histS[(b + 1) * GE2];
    int sz = next - base;
    const unsigned int* buf = bbuf + base;
    hist[t] = 0;
    __syncthreads();
    for (int e = t; e < sz; e += 256)
        atomicAdd(&hist[buf[e] >> SRCBITS], 1);
    __syncthreads();
    int deg = hist[t];
    scn[t] = deg; __syncthreads();
    for (int off = 1; off < 256; off <<= 1) {
        int u = (t >= off) ? scn[t - off] : 0;
        __syncthreads();
        scn[t] += u;
        __syncthreads();
    }
    int myoff = base + scn[t] - deg;
    int node = b * 256 + t;
    if (node < NN) {
        cnt[node]  = deg;
        offs[node] = myoff;
        float d = 1.0f / sqrtf((float)(deg + 1));
        dinv[node] = d;
        float4 xv = ((const float4*)x)[node];
        float4 o; o.x = d * xv.x; o.y = d * xv.y; o.z = d * xv.z; o.w = d * xv.w;
        ((float4*)xs)[node] = o;
    }
    cur[t] = myoff;
    __syncthreads();
    for (int e = t; e < sz; e += 256) {
        unsigned int u = buf[e];
        int p = atomicAdd(&cur[u >> SRCBITS], 1);
        csr[p] = (int)(u & SRCMASK);
    }
}

// ---- layer-1 aggregation, 8-way ILP ----------------------------------------
__global__ void k_agg1(const float* __restrict__ x, const float* __restrict__ xs,
                       const float* __restrict__ dinv, const int* __restrict__ offs,
                       const int* __restrict__ cnt, const int* __restrict__ csr,
                       float* __restrict__ agg) {
    int i = blockIdx.x * 256 + threadIdx.x;
    if (i >= NN) return;
    float sx = 0.f, sy = 0.f, sz = 0.f, sw = 0.f;
    int b = offs[i], n = cnt[i];
    int j = 0;
    for (; j + 8 <= n; j += 8) {
        int s0 = csr[b + j + 0], s1 = csr[b + j + 1], s2 = csr[b + j + 2], s3 = csr[b + j + 3];
        int s4 = csr[b + j + 4], s5 = csr[b + j + 5], s6 = csr[b + j + 6], s7 = csr[b + j + 7];
        float4 v0 = ((const float4*)xs)[s0];
        float4 v1 = ((const float4*)xs)[s1];
        float4 v2 = ((const float4*)xs)[s2];
        float4 v3 = ((const float4*)xs)[s3];
        float4 v4 = ((const float4*)xs)[s4];
        float4 v5 = ((const float4*)xs)[s5];
        float4 v6 = ((const float4*)xs)[s6];
        float4 v7 = ((const float4*)xs)[s7];
        sx += v0.x + v1.x + v2.x + v3.x + v4.x + v5.x + v6.x + v7.x;
        sy += v0.y + v1.y + v2.y + v3.y + v4.y + v5.y + v6.y + v7.y;
        sz += v0.z + v1.z + v2.z + v3.z + v4.z + v5.z + v6.z + v7.z;
        sw += v0.w + v1.w + v2.w + v3.w + v4.w + v5.w + v6.w + v7.w;
    }
    for (; j < n; ++j) {
        int s = csr[b + j];
        float4 v = ((const float4*)xs)[s];
        sx += v.x; sy += v.y; sz += v.z; sw += v.w;
    }
    float d = dinv[i];
    float4 xi = ((const float4*)x)[i];
    float4 o;
    o.x = d * (sx + d * xi.x);
    o.y = d * (sy + d * xi.y);
    o.z = d * (sz + d * xi.z);
    o.w = d * (sw + d * xi.w);
    ((float4*)agg)[i] = o;
}

// ---- h1 = relu(agg@W1 + b1); hs = bf16(dinv * (h1@W2)). 4 nodes/block ------
__global__ void k_mm(const float* __restrict__ agg, const float* __restrict__ W1,
                     const float* __restrict__ b1, const float* __restrict__ W2,
                     const float* __restrict__ dinv, unsigned short* __restrict__ hs) {
    __shared__ float sW2[64 * 64];
    __shared__ float sh1[4][64];
    int t = threadIdx.x;
#pragma unroll
    for (int r = 0; r < 16; ++r) sW2[r * 256 + t] = W2[r * 256 + t];
    int node = blockIdx.x * 4 + (t >> 6);
    int c = t & 63;
    float4 a = ((const float4*)agg)[node];
    float h = a.x * W1[c] + a.y * W1[64 + c] + a.z * W1[128 + c] + a.w * W1[192 + c];
    h = fmaxf(h + b1[c], 0.0f);
    sh1[t >> 6][c] = h;
    __syncthreads();
    const float* h1 = sh1[t >> 6];
    float sum = 0.0f;
#pragma unroll
    for (int k = 0; k < 64; ++k) sum = fmaf(h1[k], sW2[k * 64 + c], sum);
    hs[node * 64 + c] = f2bf(sum * dinv[node]);
}

// ---- layer-2 gather + head, fused, 8-way ILP, bf16 hs. One wave per node. --
__global__ void k_gather_head(const unsigned short* __restrict__ hs, const int* __restrict__ offs,
                              const int* __restrict__ cnt, const int* __restrict__ csr,
                              const float* __restrict__ dinv, const float* __restrict__ b2,
                              const float* __restrict__ Wl, const float* __restrict__ bl,
                              float* __restrict__ out) {
    int t = threadIdx.x;
    int node = blockIdx.x * 4 + (t >> 6);
    int c = t & 63;
    int b = offs[node], n = cnt[node];
    const unsigned short* hc = hs + c;
    float a = bf2f(hc[node * 64]);               // self loop (hs already *dinv[self])
    int myidx = (c < n) ? csr[b + c] : 0;        // prefetch up to 64 indices
    int m = n < 64 ? n : 64;
    int j = 0;
    float a0 = 0.f, a1 = 0.f, a2 = 0.f, a3 = 0.f;
    float a4 = 0.f, a5 = 0.f, a6 = 0.f, a7 = 0.f;
    for (; j + 8 <= m; j += 8) {
        int s0 = __shfl(myidx, j + 0, 64), s1 = __shfl(myidx, j + 1, 64);
        int s2 = __shfl(myidx, j + 2, 64), s3 = __shfl(myidx, j + 3, 64);
        int s4 = __shfl(myidx, j + 4, 64), s5 = __shfl(myidx, j + 5, 64);
        int s6 = __shfl(myidx, j + 6, 64), s7 = __shfl(myidx, j + 7, 64);
        unsigned short v0 = hc[s0 * 64], v1 = hc[s1 * 64], v2 = hc[s2 * 64], v3 = hc[s3 * 64];
        unsigned short v4 = hc[s4 * 64], v5 = hc[s5 * 64], v6 = hc[s6 * 64], v7 = hc[s7 * 64];
        a0 += bf2f(v0); a1 += bf2f(v1); a2 += bf2f(v2); a3 += bf2f(v3);
        a4 += bf2f(v4); a5 += bf2f(v5); a6 += bf2f(v6); a7 += bf2f(v7);
    }
    for (; j < m; ++j) {
        int s = __shfl(myidx, j, 64);
        a += bf2f(hc[s * 64]);
    }
    for (j = 64; j < n; ++j) {                   // rare: deg > 64
        int s = csr[b + j];
        a += bf2f(hc[s * 64]);
    }
    a += ((a0 + a1) + (a2 + a3)) + ((a4 + a5) + (a6 + a7));
    float h2 = fmaxf(fmaf(dinv[node], a, b2[c]), 0.0f);
    float v = h2 * Wl[c];
#pragma unroll
    for (int off = 32; off; off >>= 1) v += __shfl_down(v, off, 64);
    if (c == 0) out[node] = v + bl[0];
}

extern "C" void kernel_launch(void* const* d_in, const int* in_sizes, int n_in,
                              void* d_out, int out_size, void* d_ws, size_t ws_size,
                              hipStream_t stream) {
    const float* x  = (const float*)d_in[0];
    const int*   ei = (const int*)d_in[1];
    const float* W1 = (const float*)d_in[2];
    const float* b1 = (const float*)d_in[3];
    const float* W2 = (const float*)d_in[4];
    const float* b2 = (const float*)d_in[5];
    const float* Wl = (const float*)d_in[6];
    const float* bl = (const float*)d_in[7];
    float* out = (float*)d_out;

    char* w = (char*)d_ws;
    float* dinv  = (float*)w;                  w += NN * 4;
    int*   cnt   = (int*)w;                    w += NN * 4;
    int*   offs  = (int*)w;                    w += NN * 4;
    int*   csr   = (int*)w;                    w += NE * 4;
    float* xs    = (float*)w;                  w += NN * 4 * 4;
    float* agg   = (float*)w;                  w += NN * 4 * 4;
    unsigned short* hs = (unsigned short*)w;   w += (size_t)NN * HID * 2;           // 12.8 MB
    int*   histG = (int*)w;                    w += (size_t)((SCANN + 3) & ~3) * 4; // 1.22 MB
    int*   bsum  = (int*)w;                    w += 512 * 4;
    unsigned int* bbuf = (unsigned int*)w;     w += (size_t)NE * 4;                 // 6.4 MB
    int*   flag  = (int*)w;                    w += 4;    // ~31 MB total

    const int GN = (NN + 255) / 256;       // 391

    hipLaunchKernelGGL(k_detect, dim3(1),    dim3(64),  0, stream, ei, flag);
    hipLaunchKernelGGL(k_histA,  dim3(GE2),  dim3(256), 0, stream, ei, flag, histG);
    hipLaunchKernelGGL(k_scan1,  dim3(NCH),  dim3(256), 0, stream, histG, bsum);
    hipLaunchKernelGGL(k_scan2,  dim3(1),    dim3(512), 0, stream, bsum);
    hipLaunchKernelGGL(k_scan3,  dim3(NCH),  dim3(256), 0, stream, histG, bsum);
    hipLaunchKernelGGL(k_fillA,  dim3(GE2),  dim3(256), 0, stream, ei, flag, histG, bbuf);
    hipLaunchKernelGGL(k_passB,  dim3(NBUK), dim3(256), 0, stream,
                       bbuf, histG, x, cnt, offs, dinv, xs, csr);

    hipLaunchKernelGGL(k_agg1, dim3(GN), dim3(256), 0, stream,
                       x, xs, dinv, offs, cnt, csr, agg);
    hipLaunchKernelGGL(k_mm, dim3(NN / 4), dim3(256), 0, stream,
                       agg, W1, b1, W2, dinv, hs);
    hipLaunchKernelGGL(k_gather_head, dim3(NN / 4), dim3(256), 0, stream,
                       hs, offs, cnt, csr, dinv, b2, Wl, bl, out);
}